// Round 1
// baseline (11.409 us; speedup 1.0000x reference)
//
#include <hip/hip_runtime.h>
#include <hip/hip_bf16.h>

// loss = (1/T) * (1 - mean_i p_i),  p_i = dot(a_i,b_i) / (max(||a_i||,eps)*max(||b_i||,eps))
// B=4096, D=512, T=0.5, eps=1e-12

#define BATCH 4096
#define DIM 512
#define ROWS_PER_BLOCK 4   // 4 waves/block, 1 row/wave
#define NBLOCKS (BATCH / ROWS_PER_BLOCK)   // 1024

__global__ void pair_cosine_partial(const float* __restrict__ a,
                                    const float* __restrict__ b,
                                    float* __restrict__ partial) {
    const int wave = threadIdx.x >> 6;          // 0..3
    const int lane = threadIdx.x & 63;
    const int row  = blockIdx.x * ROWS_PER_BLOCK + wave;

    // D=512 floats = 128 float4 per row. Lane l reads float4[l] and float4[l+64]
    // -> two fully-coalesced 1024B wave transactions per input.
    const float4* a4 = reinterpret_cast<const float4*>(a) + (size_t)row * (DIM / 4);
    const float4* b4 = reinterpret_cast<const float4*>(b) + (size_t)row * (DIM / 4);

    float4 av0 = a4[lane];
    float4 av1 = a4[lane + 64];
    float4 bv0 = b4[lane];
    float4 bv1 = b4[lane + 64];

    float dot = av0.x * bv0.x + av0.y * bv0.y + av0.z * bv0.z + av0.w * bv0.w
              + av1.x * bv1.x + av1.y * bv1.y + av1.z * bv1.z + av1.w * bv1.w;
    float na  = av0.x * av0.x + av0.y * av0.y + av0.z * av0.z + av0.w * av0.w
              + av1.x * av1.x + av1.y * av1.y + av1.z * av1.z + av1.w * av1.w;
    float nb  = bv0.x * bv0.x + bv0.y * bv0.y + bv0.z * bv0.z + bv0.w * bv0.w
              + bv1.x * bv1.x + bv1.y * bv1.y + bv1.z * bv1.z + bv1.w * bv1.w;

    // 64-lane butterfly reduce (wave = 64 on CDNA)
    #pragma unroll
    for (int off = 32; off > 0; off >>= 1) {
        dot += __shfl_xor(dot, off);
        na  += __shfl_xor(na, off);
        nb  += __shfl_xor(nb, off);
    }

    __shared__ float s[ROWS_PER_BLOCK];
    if (lane == 0) {
        float denom = fmaxf(sqrtf(na), 1e-12f) * fmaxf(sqrtf(nb), 1e-12f);
        s[wave] = dot / denom;
    }
    __syncthreads();
    if (threadIdx.x == 0) {
        partial[blockIdx.x] = s[0] + s[1] + s[2] + s[3];
    }
}

__global__ void finalize_loss(const float* __restrict__ partial,
                              float* __restrict__ out) {
    // 1024 partials, 256 threads (4 waves)
    const int t = threadIdx.x;
    float v = partial[t] + partial[t + 256] + partial[t + 512] + partial[t + 768];
    #pragma unroll
    for (int off = 32; off > 0; off >>= 1) {
        v += __shfl_xor(v, off);
    }
    __shared__ float s[4];
    if ((t & 63) == 0) s[t >> 6] = v;
    __syncthreads();
    if (t == 0) {
        float sum_p = s[0] + s[1] + s[2] + s[3];
        float mean_p = sum_p / (float)BATCH;
        // loss = (1 - mean_p) / TEMPERATURE, TEMPERATURE = 0.5
        out[0] = (1.0f - mean_p) * 2.0f;
    }
}

extern "C" void kernel_launch(void* const* d_in, const int* in_sizes, int n_in,
                              void* d_out, int out_size, void* d_ws, size_t ws_size,
                              hipStream_t stream) {
    const float* a = (const float*)d_in[0];   // emb_i [B, D]
    const float* b = (const float*)d_in[1];   // emb_j [B, D]
    float* out = (float*)d_out;
    float* partial = (float*)d_ws;            // NBLOCKS floats

    pair_cosine_partial<<<NBLOCKS, 256, 0, stream>>>(a, b, partial);
    finalize_loss<<<1, 256, 0, stream>>>(partial, out);
}